// Round 5
// baseline (329.135 us; speedup 1.0000x reference)
//
#include <hip/hip_runtime.h>
#include <math.h>

#define BB 128
#define TT 2048
#define OO 128
#define EE 512
#define LL 34
#define XDIM 640       // O+E
#define CHUNKS 16
#define CHUNK_LEN 128  // TT / CHUNKS

__device__ __forceinline__ float sigmoidf_(float x) { return 1.0f / (1.0f + __expf(-x)); }

// ---------------- K1: LSTM cell, fused GEMM + activation.
// grid (8 o-tiles of 16, 32 batch-quads) = 256 blocks x 256 threads.
__global__ __launch_bounds__(256) void lstm_kernel(
    const float* __restrict__ y1, const float* __restrict__ c1,
    const float* __restrict__ sh1, const float* __restrict__ sc1,
    const float* __restrict__ Wih, const float* __restrict__ bih,
    const float* __restrict__ Whh, const float* __restrict__ bhh,
    float* __restrict__ out_sh, float* __restrict__ out_sc)
{
    __shared__ float xs[4][768];          // per batch row: [y1(512)|c1(128)|sh1(128)]
    __shared__ float gbuf[4][4][16];      // [gate][bi][o_local]
    const int tid = threadIdx.x;
    const int otile = blockIdx.x;
    const int qb = blockIdx.y * 4;

    for (int idx = tid; idx < 4 * 768; idx += 256) {
        int bi = idx / 768, k = idx - bi * 768;
        int b = qb + bi;
        float v;
        if (k < 512)      v = y1[b * EE + k];
        else if (k < 640) v = c1[b * OO + (k - 512)];
        else              v = sh1[b * OO + (k - 640)];
        xs[bi][k] = v;
    }
    __syncthreads();

    const int g = tid >> 6, l = tid & 63;   // wave g = gate g
    #pragma unroll 2
    for (int i = 0; i < 16; ++i) {
        const int row = g * 128 + otile * 16 + i;
        const float* wr = Wih + (size_t)row * XDIM;
        float a0 = 0.f, a1 = 0.f, a2 = 0.f, a3 = 0.f;
        #pragma unroll
        for (int j = 0; j < 10; ++j) {
            float wv = wr[l + 64 * j];
            a0 += wv * xs[0][l + 64 * j];
            a1 += wv * xs[1][l + 64 * j];
            a2 += wv * xs[2][l + 64 * j];
            a3 += wv * xs[3][l + 64 * j];
        }
        const float* wh = Whh + (size_t)row * OO;
        #pragma unroll
        for (int j = 0; j < 2; ++j) {
            float wv = wh[l + 64 * j];
            a0 += wv * xs[0][640 + l + 64 * j];
            a1 += wv * xs[1][640 + l + 64 * j];
            a2 += wv * xs[2][640 + l + 64 * j];
            a3 += wv * xs[3][640 + l + 64 * j];
        }
        #pragma unroll
        for (int off = 32; off >= 1; off >>= 1) {
            a0 += __shfl_xor(a0, off);
            a1 += __shfl_xor(a1, off);
            a2 += __shfl_xor(a2, off);
            a3 += __shfl_xor(a3, off);
        }
        if (l == 0) {
            float bb = bih[row] + bhh[row];
            gbuf[g][0][i] = a0 + bb;
            gbuf[g][1][i] = a1 + bb;
            gbuf[g][2][i] = a2 + bb;
            gbuf[g][3][i] = a3 + bb;
        }
    }
    __syncthreads();

    if (tid < 64) {
        const int bi = tid >> 4, ol = tid & 15;
        const int b = qb + bi, o = otile * 16 + ol;
        float gi = gbuf[0][bi][ol], gf = gbuf[1][bi][ol];
        float gg = gbuf[2][bi][ol], go = gbuf[3][bi][ol];
        float sc = sigmoidf_(gf) * sc1[b * OO + o] + sigmoidf_(gi) * tanhf(gg);
        float sh = sigmoidf_(go) * tanhf(sc);
        out_sc[b * OO + o] = sc;
        out_sh[b * OO + o] = sh;
    }
}

// ---------------- K2: merged scores + chunk-softmax + weighted hv sum.
// Per (b, chunk): phase A computes exp(s - m_c) weights into LDS + (m_c, S_c);
// phase B immediately accumulates the unnormalized partial c for this chunk.
__global__ __launch_bounds__(256) void attn_kernel(
    const float* __restrict__ hk, const float* __restrict__ hv,
    const float* __restrict__ mask, const float* __restrict__ sc,
    float2* __restrict__ pbuf, float* __restrict__ ws_c)
{
    const int b = blockIdx.y, chunk = blockIdx.x;
    const int tid = threadIdx.x;
    __shared__ float sm[16], ssum[16];
    __shared__ float wsh[CHUNK_LEN];
    __shared__ float pacc[8][128];

    // ---- Phase A: scores for this chunk's 128 rows.
    const int sg = tid >> 4, l = tid & 15;   // 16 subgroups x 16 lanes
    const float4 scA = *(const float4*)(sc + b * OO + l * 8);
    const float4 scB = *(const float4*)(sc + b * OO + l * 8 + 4);

    const int r0 = chunk * CHUNK_LEN + sg * 8;
    const float* mrow = mask + (size_t)b * TT + r0;
    const float* krow = hk + ((size_t)b * TT + r0) * OO;

    float s[8];
    bool val[8];
    #pragma unroll
    for (int i = 0; i < 8; ++i) {
        val[i] = (mrow[i] != 0.f);
        float4 a = make_float4(0.f, 0.f, 0.f, 0.f);
        float4 c2 = make_float4(0.f, 0.f, 0.f, 0.f);
        if (val[i]) {   // lane l covers bytes [32l, 32l+32) of the row: fully coalesced
            a  = *(const float4*)(krow + (size_t)i * OO + l * 8);
            c2 = *(const float4*)(krow + (size_t)i * OO + l * 8 + 4);
        }
        s[i] = a.x * scA.x + a.y * scA.y + a.z * scA.z + a.w * scA.w
             + c2.x * scB.x + c2.y * scB.y + c2.z * scB.z + c2.w * scB.w;
    }
    #pragma unroll
    for (int i = 0; i < 8; ++i) {
        s[i] += __shfl_xor(s[i], 8);
        s[i] += __shfl_xor(s[i], 4);
        s[i] += __shfl_xor(s[i], 2);
        s[i] += __shfl_xor(s[i], 1);
    }
    float msg = -INFINITY;
    #pragma unroll
    for (int i = 0; i < 8; ++i) if (val[i]) msg = fmaxf(msg, s[i]);
    if (l == 0) sm[sg] = msg;
    __syncthreads();
    float mc = sm[0];
    #pragma unroll
    for (int i = 1; i < 16; ++i) mc = fmaxf(mc, sm[i]);

    float psum = 0.f;
    #pragma unroll
    for (int i = 0; i < 8; ++i) {
        float e = val[i] ? __expf(s[i] - mc) : 0.f;   // mc=-inf only if no valid rows
        psum += e;
        if (l == i) wsh[sg * 8 + i] = e;
    }
    if (l == 0) ssum[sg] = psum;
    __syncthreads();
    if (tid == 0) {
        float S = 0.f;
        #pragma unroll
        for (int i = 0; i < 16; ++i) S += ssum[i];
        pbuf[(size_t)b * CHUNKS + chunk] = make_float2(mc, S);
    }

    // ---- Phase B: unnormalized weighted sum over hv with LDS weights.
    const int o4 = tid & 31, rr = tid >> 5;   // 8 row-groups x 32 o-quads
    const float* vbase = hv + ((size_t)b * TT + chunk * CHUNK_LEN) * OO + o4 * 4;
    float4 acc = make_float4(0.f, 0.f, 0.f, 0.f);
    #pragma unroll 8
    for (int j = 0; j < 16; ++j) {
        const int r = rr + 8 * j;
        const float wr = wsh[r];
        if (wr != 0.f) {
            float4 v = *(const float4*)(vbase + (size_t)r * OO);
            acc.x += wr * v.x;
            acc.y += wr * v.y;
            acc.z += wr * v.z;
            acc.w += wr * v.w;
        }
    }
    *(float4*)&pacc[rr][o4 * 4] = acc;
    __syncthreads();

    if (tid < 128) {
        float s2 = 0.f;
        #pragma unroll
        for (int i = 0; i < 8; ++i) s2 += pacc[i][tid];
        ws_c[((size_t)b * CHUNKS + chunk) * OO + tid] = s2;   // unnormalized partial
    }
}

// ---------------- K3: normalize + combine chunk partials -> c, then MLP head + softmax.
__global__ __launch_bounds__(256) void final_kernel(
    const float2* __restrict__ pbuf, const float* __restrict__ ws_c,
    const float* __restrict__ sh_in,
    const float* __restrict__ W1, const float* __restrict__ b1,
    const float* __restrict__ W2, const float* __restrict__ b2,
    const float* __restrict__ W3, const float* __restrict__ b3,
    float* __restrict__ out_p, float* __restrict__ out_c)
{
    const int b = blockIdx.x, tid = threadIdx.x;
    __shared__ float marr[CHUNKS], Sarr[CHUNKS];
    __shared__ float cbuf[128], shbuf[128], h1[LL], zz[LL], red2[2];

    if (tid < CHUNKS) {
        float2 p = pbuf[(size_t)b * CHUNKS + tid];
        marr[tid] = p.x;
        Sarr[tid] = p.y;
    }
    __syncthreads();
    float M = marr[0];
    #pragma unroll
    for (int i = 1; i < CHUNKS; ++i) M = fmaxf(M, marr[i]);
    float S = 0.f;
    #pragma unroll
    for (int i = 0; i < CHUNKS; ++i) S += Sarr[i] * __expf(marr[i] - M);
    const float invS = 1.f / S;

    if (tid < 128) {
        float s = 0.f;
        const float* base = ws_c + (size_t)b * CHUNKS * OO + tid;
        #pragma unroll
        for (int i = 0; i < CHUNKS; ++i)
            s += base[i * OO] * __expf(marr[i] - M);   // -inf -> 0 for dead chunk
        s *= invS;
        cbuf[tid] = s;
        out_c[b * OO + tid] = s;
        shbuf[tid] = sh_in[b * OO + tid];
    }
    __syncthreads();

    const int o = tid >> 2, l2 = tid & 3;
    if (o < LL) {
        float a = 0.f;
        const float* w1r = W1 + o * OO;
        const float* w2r = W2 + o * OO;
        #pragma unroll 8
        for (int j = 0; j < 32; ++j) {
            int k = l2 + 4 * j;
            a += w1r[k] * shbuf[k] + w2r[k] * cbuf[k];
        }
        a += __shfl_xor(a, 1);
        a += __shfl_xor(a, 2);
        if (l2 == 0) h1[o] = fmaxf(a + b1[o] + b2[o], 0.f);
    }
    __syncthreads();

    if (o < LL) {
        float z = 0.f;
        const float* w3r = W3 + o * LL;
        for (int j = 0; j < 9; ++j) {
            int k = l2 + 4 * j;
            if (k < LL) z += w3r[k] * h1[k];
        }
        z += __shfl_xor(z, 1);
        z += __shfl_xor(z, 2);
        if (l2 == 0) zz[o] = z + b3[o];
    }
    __syncthreads();
    if (tid == 0) {
        float mm = zz[0];
        for (int i = 1; i < LL; i++) mm = fmaxf(mm, zz[i]);
        float ss = 0.f;
        for (int i = 0; i < LL; i++) ss += __expf(zz[i] - mm);
        red2[0] = mm; red2[1] = ss;
    }
    __syncthreads();
    if (tid < LL) out_p[b * LL + tid] = __expf(zz[tid] - red2[0]) / red2[1];
}

extern "C" void kernel_launch(void* const* d_in, const int* in_sizes, int n_in,
                              void* d_out, int out_size, void* d_ws, size_t ws_size,
                              hipStream_t stream) {
    (void)in_sizes; (void)n_in; (void)out_size; (void)ws_size;
    const float* hk   = (const float*)d_in[0];
    const float* hv   = (const float*)d_in[1];
    const float* y1   = (const float*)d_in[2];
    const float* c1   = (const float*)d_in[3];
    const float* sh1  = (const float*)d_in[4];
    const float* sc1  = (const float*)d_in[5];
    const float* mask = (const float*)d_in[6];
    const float* Wih  = (const float*)d_in[7];
    const float* bih  = (const float*)d_in[8];
    const float* Whh  = (const float*)d_in[9];
    const float* bhh  = (const float*)d_in[10];
    const float* W1   = (const float*)d_in[11];
    const float* b1   = (const float*)d_in[12];
    const float* W2   = (const float*)d_in[13];
    const float* b2   = (const float*)d_in[14];
    const float* W3   = (const float*)d_in[15];
    const float* b3   = (const float*)d_in[16];

    float* out    = (float*)d_out;        // [B, L]
    float* out_c  = out + BB * LL;        // [B, O]
    float* out_sh = out_c + BB * OO;      // [B, O]
    float* out_sc = out_sh + BB * OO;     // [B, O]

    float*  ws_c = (float*)d_ws;                          // [B, CHUNKS, O] partials (1 MB)
    float2* pbuf = (float2*)(ws_c + (size_t)BB * CHUNKS * OO);  // [B, CHUNKS] (m,S) 16 KB

    lstm_kernel<<<dim3(8, 32), 256, 0, stream>>>(y1, c1, sh1, sc1, Wih, bih, Whh, bhh,
                                                 out_sh, out_sc);
    attn_kernel<<<dim3(CHUNKS, BB), 256, 0, stream>>>(hk, hv, mask, out_sc, pbuf, ws_c);
    final_kernel<<<BB, 256, 0, stream>>>(pbuf, ws_c, out_sh, W1, b1, W2, b2, W3, b3,
                                         out, out_c);
}